// Round 14
// baseline (193.918 us; speedup 1.0000x reference)
//
#include <hip/hip_runtime.h>

// Problem constants (match reference)
#define NB  2      // batches
#define NP  8192   // points per batch
#define IMH 256
#define IMW 256
#define NBKT 1024  // x-buckets per batch
#define CAP 128    // bin capacity; central buckets ~51 (Poisson), max ~80; 128 safe

constexpr float R2F = 0.01f;      // RADIUS^2 (np weak promotion -> f32)
constexpr float BK_SCALE = 64.f;  // bucket width 1/64 over x in [-8, 8)
constexpr float BK_OFF   = 8.f;
#define BK_PAD 7                  // ceil(0.1001 * 64) = 7  (conservative cull)

__device__ __forceinline__ int bucket_of(float x) {
    int b = (int)floorf((x + BK_OFF) * BK_SCALE);
    return min(max(b, 0), NBKT - 1);
}

// numpy sq recipe: rounded muls, sequential adds, NO fma (deterministic).
__device__ __forceinline__ float sq_np(float x, float y, float z) {
    return __fadd_rn(__fadd_rn(__fmul_rn(x, x), __fmul_rn(y, y)),
                     __fmul_rn(z, z));
}

// ---------------------------------------------------------------------------
// Kernel A: capacity-binned fill (R13-passing, verbatim). Wide, ~1us.
// counts/img_c/img_w pre-zeroed by the single memset node.
// ---------------------------------------------------------------------------
__global__ __launch_bounds__(256) void binfill_kernel(
    const float* __restrict__ pts, float4* __restrict__ bins,
    int* __restrict__ counts)
{
    const int t = blockIdx.x * 256 + threadIdx.x;     // 0 .. NB*NP-1
    const int b = t >> 13, i = t & (NP - 1);
    const float x = pts[(size_t)t * 3 + 0];
    const float y = pts[(size_t)t * 3 + 1];
    const float z = pts[(size_t)t * 3 + 2];
    const int g = (b << 10) + bucket_of(x);
    const int slot = atomicAdd(&counts[g], 1);
    if (slot < CAP)
        bins[(size_t)g * CAP + slot] = make_float4(x, y, z, __int_as_float(i));
}

// ---------------------------------------------------------------------------
// Kernel B: fused windowed density + elliptical splat (R13 math verbatim;
// R13->R14 geometry fix: 256-thr blocks, wave = one bucket, looping its
// slot-groups; window counts/pointers hoisted once per wave).
//   dot = fma(z*z', fma(y*y', rn(x*x')));  d2 = (sq_i+sq_j) - 2*dot
//   include iff max(d2,0) <= 0.01f;  w = expf((d2c/0.01f) * -0.25f)
// ---------------------------------------------------------------------------
__global__ __launch_bounds__(256) void densplat_kernel(
    const float4* __restrict__ bins, const int* __restrict__ counts,
    const float* __restrict__ proj, const float* __restrict__ ell,
    const float* __restrict__ cols,
    float* __restrict__ img_c, float* __restrict__ img_w)
{
    const int wave = threadIdx.x >> 6, lane = threadIdx.x & 63;
    const int bk = blockIdx.x * 4 + wave;             // 0 .. 2047 (this wave's bucket)
    const int b  = bk >> 10, kb = bk & (NBKT - 1);
    const int cnt = min(counts[bk], CAP);
    if (cnt == 0) return;                             // wave-uniform retire

    // hoist window counts & bases (wave-uniform, up to 15 buckets)
    const int jb0 = max(kb - BK_PAD, 0), jb1 = min(kb + BK_PAD, NBKT - 1);
    int cj[15]; const float4* bp[15];
    const int nw = jb1 - jb0 + 1;
    for (int m = 0; m < nw; ++m) {
        const int gj = (b << 10) + (jb0 + m);
        cj[m] = min(counts[gj], CAP);
        bp[m] = bins + (size_t)gj * CAP;
    }
    const int ownm = kb - jb0;                        // own bucket's window idx

    for (int s0 = 0; s0 < cnt; s0 += 8) {             // slot groups of 8
        const int nv = min(8, cnt - s0);

        float xi[8], yi[8], zi[8], sqi[8], sum[8];
        int   oi[8];
        #pragma unroll
        for (int u = 0; u < 8; ++u) {
            const int si = s0 + min(u, nv - 1);       // clamp (dup discarded)
            const float4 p = bins[(size_t)bk * CAP + si];
            xi[u] = p.x; yi[u] = p.y; zi[u] = p.z;
            sqi[u] = sq_np(p.x, p.y, p.z);
            oi[u] = __float_as_int(p.w);
            sum[u] = 0.f;
        }

        for (int m = 0; m < nw; ++m) {
            const bool own = (m == ownm);
            const float4* __restrict__ bj = bp[m];
            const int c = cj[m];
            for (int jj = lane; jj < c; jj += 64) {
                const float4 pj = bj[jj];
                const float sqj = sq_np(pj.x, pj.y, pj.z);
                #pragma unroll
                for (int u = 0; u < 8; ++u) {
                    const float dot = __fmaf_rn(zi[u], pj.z,
                                      __fmaf_rn(yi[u], pj.y,
                                      __fmul_rn(xi[u], pj.x)));
                    const float d2 = __fsub_rn(__fadd_rn(sqi[u], sqj),
                                               __fadd_rn(dot, dot));
                    const float d2c = fmaxf(d2, 0.f);
                    if (!(own && jj == s0 + u) && d2c <= R2F)
                        sum[u] += expf(__fmul_rn(__fdiv_rn(d2c, R2F), -0.25f));
                }
            }
        }

        // per-point reduce + broadcast + splat (R7/R13 splat math verbatim)
        for (int u = 0; u < nv; ++u) {
            float s = sum[u];
            #pragma unroll
            for (int off2 = 32; off2; off2 >>= 1) s += __shfl_down(s, off2, 64);
            const float dens = __shfl(s, 0, 64);
            if (dens == 0.f) continue;                // exact-zero contribution

            const size_t gp = (size_t)b * NP + oi[u];
            const float x = proj[gp * 2 + 0], y = proj[gp * 2 + 1];
            const float a  = ell[gp * 3 + 0], bb = ell[gp * 3 + 1], c = ell[gp * 3 + 2];
            const float cr = cols[gp * 3 + 0], cg = cols[gp * 3 + 1], cb = cols[gp * 3 + 2];

            const float den = __fsub_rn(__fmul_rn(__fmul_rn(4.f, a), bb),
                                        __fmul_rn(c, c));
            const float xE = fminf(__fsqrt_rn(__fdiv_rn(__fmul_rn(4.f, bb), den)), 15.f);
            const float yE = fminf(__fsqrt_rn(__fdiv_rn(__fmul_rn(4.f, a),  den)), 15.f);
            const float xEp1 = __fadd_rn(xE, 1.f);
            const float yEp1 = __fadd_rn(yE, 1.f);
            const float x0 = floorf(x), y0 = floorf(y);

            for (int idx = lane; idx < 81; idx += 64) {
                const float ox = (float)(idx / 9) - 4.f;  // 'ij': ox slow axis
                const float oy = (float)(idx % 9) - 4.f;
                const float px = __fadd_rn(x0, ox);       // exact (small ints)
                const float py = __fadd_rn(y0, oy);
                if (px < 0.f || px >= 256.f || py < 0.f || py >= 256.f) continue;
                const float dx = __fsub_rn(px, x);
                const float dy = __fsub_rn(py, y);
                if (fabsf(dx) > xEp1 || fabsf(dy) > yEp1) continue;
                const float Q = __fadd_rn(__fadd_rn(
                                    __fmul_rn(__fmul_rn(a, dx), dx),
                                    __fmul_rn(__fmul_rn(bb, dy), dy)),
                                  __fmul_rn(__fmul_rn(c, dx), dy));
                if (!(Q <= 1.0f)) continue;
                const float wgt = __fmul_rn(expf(__fmul_rn(-0.5f, Q)), dens);
                const int pxi = (int)px, pyi = (int)py;
                const int flat = ((b << 8) + pyi) * IMW + pxi;
                atomicAdd(&img_c[flat * 3 + 0], __fmul_rn(wgt, cr));
                atomicAdd(&img_c[flat * 3 + 1], __fmul_rn(wgt, cg));
                atomicAdd(&img_c[flat * 3 + 2], __fmul_rn(wgt, cb));
                atomicAdd(&img_w[flat],         wgt);
            }
        }
    }
}

// ---------------------------------------------------------------------------
// Kernel C: normalize from workspace accumulators into d_out (fresh write,
// no d_out pre-zero needed): out = img_c_ws / (img_w + eps)
// ---------------------------------------------------------------------------
__global__ __launch_bounds__(256) void norm_kernel(
    float* __restrict__ out, const float* __restrict__ img_c,
    const float* __restrict__ img_w)
{
    const int p = blockIdx.x * 256 + threadIdx.x;
    if (p < NB * IMH * IMW) {
        const float d = __fadd_rn(img_w[p], 1e-8f);
        out[3 * p + 0] = __fdiv_rn(img_c[3 * p + 0], d);
        out[3 * p + 1] = __fdiv_rn(img_c[3 * p + 1], d);
        out[3 * p + 2] = __fdiv_rn(img_c[3 * p + 2], d);
    }
}

extern "C" void kernel_launch(void* const* d_in, const int* in_sizes, int n_in,
                              void* d_out, int out_size, void* d_ws, size_t ws_size,
                              hipStream_t stream)
{
    const float* points = (const float*)d_in[0];   // [NB,NP,3]
    const float* proj   = (const float*)d_in[1];   // [NB,NP,2]
    const float* ell    = (const float*)d_in[2];   // [NB,NP,3]
    const float* cols   = (const float*)d_in[3];   // [NB,NP,3]
    float* out = (float*)d_out;                    // [NB,IMH,IMW,3]

    // workspace: bins (4MB) | [img_c 1.5MB | img_w 0.5MB | counts 8KB] <- one memset
    float4* bins   = (float4*)d_ws;                            // 2048*CAP f4
    float*  img_c  = (float*)(bins + (size_t)NB * NBKT * CAP); // 393216 f
    float*  img_w  = img_c + (size_t)NB * IMH * IMW * 3;       // 131072 f
    int*    counts = (int*)(img_w + (size_t)NB * IMH * IMW);   // 2048 i
    const size_t zero_bytes = sizeof(float) * ((size_t)NB * IMH * IMW * 4)
                            + sizeof(int) * (NB * NBKT);

    hipMemsetAsync(img_c, 0, zero_bytes, stream);
    binfill_kernel <<<NB * NP / 256, 256, 0, stream>>>(points, bins, counts);
    densplat_kernel<<<NB * NBKT / 4, 256, 0, stream>>>(bins, counts,
                                                       proj, ell, cols,
                                                       img_c, img_w);
    norm_kernel    <<<(NB * IMH * IMW + 255) / 256, 256, 0, stream>>>(out, img_c, img_w);
}

// Round 15
// 58.529 us; speedup vs baseline: 3.3132x; 3.3132x over previous
//
#include <hip/hip_runtime.h>

// Problem constants (match reference)
#define NB  2      // batches
#define NP  8192   // points per batch
#define IMH 256
#define IMW 256
#define NBKT 1024  // x-buckets per batch
#define CAP 128    // bin capacity; central buckets ~51 (Poisson), max ~80; 128 safe

constexpr float R2F = 0.01f;      // RADIUS^2 (np weak promotion -> f32)
constexpr float BK_SCALE = 64.f;  // bucket width 1/64 over x in [-8, 8)
constexpr float BK_OFF   = 8.f;
#define BK_PAD 7                  // ceil(0.1001 * 64) = 7  (conservative cull)

__device__ __forceinline__ int bucket_of(float x) {
    int b = (int)floorf((x + BK_OFF) * BK_SCALE);
    return min(max(b, 0), NBKT - 1);
}

// numpy sq recipe: rounded muls, sequential adds, NO fma (deterministic).
__device__ __forceinline__ float sq_np(float x, float y, float z) {
    return __fadd_rn(__fadd_rn(__fmul_rn(x, x), __fmul_rn(y, y)),
                     __fmul_rn(z, z));
}

// ---------------------------------------------------------------------------
// Kernel A: capacity-binned fill (R13-passing, verbatim). Wide, ~1us.
// counts/img_c/img_w pre-zeroed by the single memset node.
// ---------------------------------------------------------------------------
__global__ __launch_bounds__(256) void binfill_kernel(
    const float* __restrict__ pts, float4* __restrict__ bins,
    int* __restrict__ counts)
{
    const int t = blockIdx.x * 256 + threadIdx.x;     // 0 .. NB*NP-1
    const int b = t >> 13, i = t & (NP - 1);
    const float x = pts[(size_t)t * 3 + 0];
    const float y = pts[(size_t)t * 3 + 1];
    const float z = pts[(size_t)t * 3 + 2];
    const int g = (b << 10) + bucket_of(x);
    const int slot = atomicAdd(&counts[g], 1);
    if (slot < CAP)
        bins[(size_t)g * CAP + slot] = make_float4(x, y, z, __int_as_float(i));
}

// ---------------------------------------------------------------------------
// Kernel B: fused windowed density + elliptical splat — R13 inner code
// VERBATIM (no hoist arrays, counts read inline). R14->R15 geometry fix:
// 256-thr blocks; block q=blockIdx&3 of bucket bk=blockIdx>>2; wave u
// handles slot-group g=q*4+u (s0=g*8). One group per wave (R13's proven
// balance), zero idle-wave ballast, 8192 blocks for HW load balancing.
// ---------------------------------------------------------------------------
__global__ __launch_bounds__(256) void densplat_kernel(
    const float4* __restrict__ bins, const int* __restrict__ counts,
    const float* __restrict__ proj, const float* __restrict__ ell,
    const float* __restrict__ cols,
    float* __restrict__ img_c, float* __restrict__ img_w)
{
    const int wave = threadIdx.x >> 6, lane = threadIdx.x & 63;
    const int bk = blockIdx.x >> 2;                   // 0 .. 2047
    const int q  = blockIdx.x & 3;
    const int b  = bk >> 10, kb = bk & (NBKT - 1);
    const int cnt = min(counts[bk], CAP);
    const int s0  = (q * 4 + wave) * 8;               // this wave's slot group
    if (s0 >= cnt) return;                            // wave-uniform retire
    const int nv = min(8, cnt - s0);                  // valid i's in group

    float xi[8], yi[8], zi[8], sqi[8], sum[8];
    int   oi[8];
    #pragma unroll
    for (int u = 0; u < 8; ++u) {
        const int si = s0 + min(u, nv - 1);           // clamp (dup discarded)
        const float4 p = bins[(size_t)bk * CAP + si];
        xi[u] = p.x; yi[u] = p.y; zi[u] = p.z;
        sqi[u] = sq_np(p.x, p.y, p.z);
        oi[u] = __float_as_int(p.w);
        sum[u] = 0.f;
    }

    const int jb0 = max(kb - BK_PAD, 0), jb1 = min(kb + BK_PAD, NBKT - 1);
    for (int jb = jb0; jb <= jb1; ++jb) {
        const int gj = (b << 10) + jb;
        const int cj = min(counts[gj], CAP);
        const float4* __restrict__ bp = bins + (size_t)gj * CAP;
        const bool own = (jb == kb);
        for (int jj = lane; jj < cj; jj += 64) {
            const float4 pj = bp[jj];
            const float sqj = sq_np(pj.x, pj.y, pj.z);
            #pragma unroll
            for (int u = 0; u < 8; ++u) {
                const float dot = __fmaf_rn(zi[u], pj.z,
                                  __fmaf_rn(yi[u], pj.y,
                                  __fmul_rn(xi[u], pj.x)));
                const float d2 = __fsub_rn(__fadd_rn(sqi[u], sqj),
                                           __fadd_rn(dot, dot));
                const float d2c = fmaxf(d2, 0.f);
                if (!(own && jj == s0 + u) && d2c <= R2F)
                    sum[u] += expf(__fmul_rn(__fdiv_rn(d2c, R2F), -0.25f));
            }
        }
    }

    // per-point reduce + broadcast + splat (R7/R13 splat math verbatim)
    for (int u = 0; u < nv; ++u) {
        float s = sum[u];
        #pragma unroll
        for (int off2 = 32; off2; off2 >>= 1) s += __shfl_down(s, off2, 64);
        const float dens = __shfl(s, 0, 64);
        if (dens == 0.f) continue;                    // exact-zero contribution

        const size_t gp = (size_t)b * NP + oi[u];
        const float x = proj[gp * 2 + 0], y = proj[gp * 2 + 1];
        const float a  = ell[gp * 3 + 0], bb = ell[gp * 3 + 1], c = ell[gp * 3 + 2];
        const float cr = cols[gp * 3 + 0], cg = cols[gp * 3 + 1], cb = cols[gp * 3 + 2];

        const float den = __fsub_rn(__fmul_rn(__fmul_rn(4.f, a), bb),
                                    __fmul_rn(c, c));
        const float xE = fminf(__fsqrt_rn(__fdiv_rn(__fmul_rn(4.f, bb), den)), 15.f);
        const float yE = fminf(__fsqrt_rn(__fdiv_rn(__fmul_rn(4.f, a),  den)), 15.f);
        const float xEp1 = __fadd_rn(xE, 1.f);
        const float yEp1 = __fadd_rn(yE, 1.f);
        const float x0 = floorf(x), y0 = floorf(y);

        for (int idx = lane; idx < 81; idx += 64) {
            const float ox = (float)(idx / 9) - 4.f;  // meshgrid 'ij': ox slow
            const float oy = (float)(idx % 9) - 4.f;
            const float px = __fadd_rn(x0, ox);       // exact (small ints)
            const float py = __fadd_rn(y0, oy);
            if (px < 0.f || px >= 256.f || py < 0.f || py >= 256.f) continue;
            const float dx = __fsub_rn(px, x);
            const float dy = __fsub_rn(py, y);
            if (fabsf(dx) > xEp1 || fabsf(dy) > yEp1) continue;
            const float Q = __fadd_rn(__fadd_rn(
                                __fmul_rn(__fmul_rn(a, dx), dx),
                                __fmul_rn(__fmul_rn(bb, dy), dy)),
                              __fmul_rn(__fmul_rn(c, dx), dy));
            if (!(Q <= 1.0f)) continue;
            const float wgt = __fmul_rn(expf(__fmul_rn(-0.5f, Q)), dens);
            const int pxi = (int)px, pyi = (int)py;
            const int flat = ((b << 8) + pyi) * IMW + pxi;
            atomicAdd(&img_c[flat * 3 + 0], __fmul_rn(wgt, cr));
            atomicAdd(&img_c[flat * 3 + 1], __fmul_rn(wgt, cg));
            atomicAdd(&img_c[flat * 3 + 2], __fmul_rn(wgt, cb));
            atomicAdd(&img_w[flat],         wgt);
        }
    }
}

// ---------------------------------------------------------------------------
// Kernel C: normalize from workspace accumulators into d_out (fresh write,
// no d_out pre-zero needed): out = img_c_ws / (img_w + eps)
// ---------------------------------------------------------------------------
__global__ __launch_bounds__(256) void norm_kernel(
    float* __restrict__ out, const float* __restrict__ img_c,
    const float* __restrict__ img_w)
{
    const int p = blockIdx.x * 256 + threadIdx.x;
    if (p < NB * IMH * IMW) {
        const float d = __fadd_rn(img_w[p], 1e-8f);
        out[3 * p + 0] = __fdiv_rn(img_c[3 * p + 0], d);
        out[3 * p + 1] = __fdiv_rn(img_c[3 * p + 1], d);
        out[3 * p + 2] = __fdiv_rn(img_c[3 * p + 2], d);
    }
}

extern "C" void kernel_launch(void* const* d_in, const int* in_sizes, int n_in,
                              void* d_out, int out_size, void* d_ws, size_t ws_size,
                              hipStream_t stream)
{
    const float* points = (const float*)d_in[0];   // [NB,NP,3]
    const float* proj   = (const float*)d_in[1];   // [NB,NP,2]
    const float* ell    = (const float*)d_in[2];   // [NB,NP,3]
    const float* cols   = (const float*)d_in[3];   // [NB,NP,3]
    float* out = (float*)d_out;                    // [NB,IMH,IMW,3]

    // workspace: bins (4MB) | [img_c 1.5MB | img_w 0.5MB | counts 8KB] <- one memset
    float4* bins   = (float4*)d_ws;                            // 2048*CAP f4
    float*  img_c  = (float*)(bins + (size_t)NB * NBKT * CAP); // 393216 f
    float*  img_w  = img_c + (size_t)NB * IMH * IMW * 3;       // 131072 f
    int*    counts = (int*)(img_w + (size_t)NB * IMH * IMW);   // 2048 i
    const size_t zero_bytes = sizeof(float) * ((size_t)NB * IMH * IMW * 4)
                            + sizeof(int) * (NB * NBKT);

    hipMemsetAsync(img_c, 0, zero_bytes, stream);
    binfill_kernel <<<NB * NP / 256, 256, 0, stream>>>(points, bins, counts);
    densplat_kernel<<<NB * NBKT * 4, 256, 0, stream>>>(bins, counts,
                                                       proj, ell, cols,
                                                       img_c, img_w);
    norm_kernel    <<<(NB * IMH * IMW + 255) / 256, 256, 0, stream>>>(out, img_c, img_w);
}